// Round 1
// baseline (1838.899 us; speedup 1.0000x reference)
//
#include <hip/hip_runtime.h>
#include <math.h>

#define SEQ_L 4096
#define HDIM 30
#define HP 32            // padded hidden (pads are kept at 0.0f)
#define NGATE 90
#define DEC_N 100

// One block, one wave. Lane j < 30 owns hidden unit j.
// Sequential recurrence: latency-bound, so everything lives in regs/LDS.
__global__ __launch_bounds__(64, 1) void seq2seq_gru_kernel(
    const float* __restrict__ x,
    const float* __restrict__ eWih, const float* __restrict__ eWhh,
    const float* __restrict__ ebih, const float* __restrict__ ebhh,
    const float* __restrict__ dWih, const float* __restrict__ dWhh,
    const float* __restrict__ dbih, const float* __restrict__ dbhh,
    const float* __restrict__ linW, const float* __restrict__ linb,
    float* __restrict__ out)
{
    const int t = threadIdx.x;
    __shared__ __align__(16) float xs[SEQ_L];
    __shared__ __align__(16) float hs[HP];     // hidden state (padded, pads=0)
    __shared__ __align__(16) float hxs[HP];    // decoder "input" vector
    __shared__ __align__(16) float dWih_s[NGATE * HP]; // dec Wih, rows padded to 32

    // ---- stage x and decoder Wih into LDS ----
    for (int i = t; i < SEQ_L; i += 64) xs[i] = x[i];
    for (int i = t; i < NGATE * HP; i += 64) {
        int r = i >> 5, c = i & 31;
        dWih_s[i] = (c < HDIM) ? dWih[r * HDIM + c] : 0.0f;
    }
    if (t < HP) { hs[t] = 0.0f; hxs[t] = 0.0f; }

    const int j = t;
    const bool act = (t < HDIM);

    // ---- encoder weights into registers (rows padded with zeros) ----
    float wr[HP], wz[HP], wn[HP];
    #pragma unroll
    for (int k = 0; k < HP; ++k) { wr[k] = 0.f; wz[k] = 0.f; wn[k] = 0.f; }
    float wir = 0.f, wiz = 0.f, win = 0.f;
    float bir = 0.f, biz = 0.f, bin_ = 0.f;
    float bhr = 0.f, bhz = 0.f, bhn = 0.f;
    float lwj = 0.f;
    if (act) {
        #pragma unroll 1
        for (int k = 0; k < HDIM; ++k) {
            wr[k] = eWhh[(j          ) * HDIM + k];
            wz[k] = eWhh[(j +   HDIM ) * HDIM + k];
            wn[k] = eWhh[(j + 2*HDIM ) * HDIM + k];
        }
        wir = eWih[j]; wiz = eWih[j + HDIM]; win = eWih[j + 2*HDIM];
        bir = ebih[j]; biz = ebih[j + HDIM]; bin_ = ebih[j + 2*HDIM];
        bhr = ebhh[j]; bhz = ebhh[j + HDIM]; bhn = ebhh[j + 2*HDIM];
        lwj = linW[j];
    }
    const float lb = linb[0];
    float hj = 0.f;                 // this lane's own hidden component
    __syncthreads();

    // ================= encoder: 4096 sequential GRU steps =================
    for (int s = 0; s < SEQ_L; ++s) {
        float hv[HP];
        {
            const float4* h4 = (const float4*)hs;   // broadcast reads
            #pragma unroll
            for (int q = 0; q < 8; ++q) {
                float4 v = h4[q];
                hv[4*q+0] = v.x; hv[4*q+1] = v.y; hv[4*q+2] = v.z; hv[4*q+3] = v.w;
            }
        }
        float xr = xs[s];
        float ar = bhr, az = bhz, an = bhn;
        #pragma unroll
        for (int k = 0; k < HP; ++k) {
            ar = fmaf(wr[k], hv[k], ar);
            az = fmaf(wz[k], hv[k], az);
            an = fmaf(wn[k], hv[k], an);
        }
        float ir  = fmaf(xr, wir, bir);
        float iz  = fmaf(xr, wiz, biz);
        float inn = fmaf(xr, win, bin_);
        float rg = 1.f / (1.f + expf(-(ir + ar)));
        float zg = 1.f / (1.f + expf(-(iz + az)));
        float ng = tanhf(fmaf(rg, an, inn));
        float hnew = (1.f - zg) * ng + zg * hj;
        hj = hnew;
        // single wave: all lanes finished their reads of hs before this point
        if (act) hs[j] = hnew;
        __syncthreads();
    }

    // ================= decoder setup =================
    if (act) { hxs[j] = hj; hs[j] = 1.0f; }   // carry = (h_enc, ones)
    float hhj = 1.0f;
    // reload recurrent weights/biases from decoder GRU
    if (act) {
        #pragma unroll 1
        for (int k = 0; k < HDIM; ++k) {
            wr[k] = dWhh[(j          ) * HDIM + k];
            wz[k] = dWhh[(j +   HDIM ) * HDIM + k];
            wn[k] = dWhh[(j + 2*HDIM ) * HDIM + k];
        }
        bir = dbih[j]; biz = dbih[j + HDIM]; bin_ = dbih[j + 2*HDIM];
        bhr = dbhh[j]; bhz = dbhh[j + HDIM]; bhn = dbhh[j + 2*HDIM];
    }
    const int jj = act ? j : 0;   // clamp LDS row index for inactive lanes
    __syncthreads();

    // ================= decoder: 100 sequential GRU steps =================
    for (int s2 = 0; s2 < DEC_N; ++s2) {
        float hv[HP], hx[HP];
        {
            const float4* h4 = (const float4*)hs;
            const float4* x4 = (const float4*)hxs;
            #pragma unroll
            for (int q = 0; q < 8; ++q) {
                float4 v = h4[q];
                hv[4*q+0] = v.x; hv[4*q+1] = v.y; hv[4*q+2] = v.z; hv[4*q+3] = v.w;
                float4 u = x4[q];
                hx[4*q+0] = u.x; hx[4*q+1] = u.y; hx[4*q+2] = u.z; hx[4*q+3] = u.w;
            }
        }
        // recurrent part from registers
        float ar = bhr, az = bhz, an = bhn;
        #pragma unroll
        for (int k = 0; k < HP; ++k) {
            ar = fmaf(wr[k], hv[k], ar);
            az = fmaf(wz[k], hv[k], az);
            an = fmaf(wn[k], hv[k], an);
        }
        // input part: dec Wih rows from LDS (per-lane rows, padded)
        float ir = bir, iz = biz, inn = bin_;
        {
            const float4* wrw = (const float4*)&dWih_s[(jj          ) * HP];
            const float4* wzw = (const float4*)&dWih_s[(jj +   HDIM ) * HP];
            const float4* wnw = (const float4*)&dWih_s[(jj + 2*HDIM ) * HP];
            #pragma unroll
            for (int q = 0; q < 8; ++q) {
                float4 a = wrw[q], b = wzw[q], c = wnw[q];
                ir  = fmaf(a.x, hx[4*q+0], ir);
                ir  = fmaf(a.y, hx[4*q+1], ir);
                ir  = fmaf(a.z, hx[4*q+2], ir);
                ir  = fmaf(a.w, hx[4*q+3], ir);
                iz  = fmaf(b.x, hx[4*q+0], iz);
                iz  = fmaf(b.y, hx[4*q+1], iz);
                iz  = fmaf(b.z, hx[4*q+2], iz);
                iz  = fmaf(b.w, hx[4*q+3], iz);
                inn = fmaf(c.x, hx[4*q+0], inn);
                inn = fmaf(c.y, hx[4*q+1], inn);
                inn = fmaf(c.z, hx[4*q+2], inn);
                inn = fmaf(c.w, hx[4*q+3], inn);
            }
        }
        float rg = 1.f / (1.f + expf(-(ir + ar)));
        float zg = 1.f / (1.f + expf(-(iz + az)));
        float ng = tanhf(fmaf(rg, an, inn));
        float hnew = (1.f - zg) * ng + zg * hhj;
        hhj = hnew;

        // res[s2] = linW . h_new + lin_b   (wave tree-reduction)
        float contrib = act ? lwj * hnew : 0.f;
        #pragma unroll
        for (int m = 32; m >= 1; m >>= 1) contrib += __shfl_xor(contrib, m, 64);
        if (t == 0) out[s2] = contrib + lb;

        if (act) { hs[j] = hnew; hxs[j] = hnew; }
        __syncthreads();
    }
}

extern "C" void kernel_launch(void* const* d_in, const int* in_sizes, int n_in,
                              void* d_out, int out_size, void* d_ws, size_t ws_size,
                              hipStream_t stream) {
    (void)in_sizes; (void)n_in; (void)d_ws; (void)ws_size; (void)out_size;
    seq2seq_gru_kernel<<<dim3(1), dim3(64), 0, stream>>>(
        (const float*)d_in[0],
        (const float*)d_in[1], (const float*)d_in[2],
        (const float*)d_in[3], (const float*)d_in[4],
        (const float*)d_in[5], (const float*)d_in[6],
        (const float*)d_in[7], (const float*)d_in[8],
        (const float*)d_in[9], (const float*)d_in[10],
        (float*)d_out);
}

// Round 2
// 1332.530 us; speedup vs baseline: 1.3800x; 1.3800x over previous
//
#include <hip/hip_runtime.h>
#include <math.h>

#define SEQ_L 4096
#define HDIM 30
#define DEC_N 100

// Branch-free fast activations via v_exp_f32 (exp2) + v_rcp_f32.
// Saturate correctly: exp2(+inf)=inf -> rcp=0; exp2(-inf)=0 -> rcp(1)=1.
__device__ __forceinline__ float fast_sig(float v) {
    float e = __builtin_amdgcn_exp2f(v * -1.44269504088896340736f); // exp(-v)
    return __builtin_amdgcn_rcpf(1.0f + e);
}
__device__ __forceinline__ float fast_tanh(float v) {
    float e = __builtin_amdgcn_exp2f(v * 2.88539008177792681472f); // exp(2v)
    return 1.0f - 2.0f * __builtin_amdgcn_rcpf(1.0f + e);
}
__device__ __forceinline__ float bcast_lane(float v, int lane) {
    return __uint_as_float(__builtin_amdgcn_readlane(__float_as_uint(v), lane));
}

// One block, one wave. Lane j<30 owns hidden unit j. The hidden state is
// broadcast every step via v_readlane into wave-uniform SGPRs — no LDS, no
// barrier on the serial recurrence path.
__global__ __launch_bounds__(64, 1) void seq2seq_gru_kernel(
    const float* __restrict__ x,
    const float* __restrict__ eWih, const float* __restrict__ eWhh,
    const float* __restrict__ ebih, const float* __restrict__ ebhh,
    const float* __restrict__ dWih, const float* __restrict__ dWhh,
    const float* __restrict__ dbih, const float* __restrict__ dbhh,
    const float* __restrict__ linW, const float* __restrict__ linb,
    float* __restrict__ out)
{
    const int t = threadIdx.x;
    __shared__ __align__(16) float xs[SEQ_L];

    // ---- one-time: stage x into LDS (vectorized) ----
    {
        const float4* x4 = (const float4*)x;
        float4* s4 = (float4*)xs;
        for (int i = t; i < SEQ_L / 4; i += 64) s4[i] = x4[i];
    }

    // Lanes >= 30 mirror lane 29 (clamped index): they compute identical,
    // harmless values and are never read back.
    const int j = (t < HDIM) ? t : (HDIM - 1);
    const bool act = (t < HDIM);

    // ---- encoder weights into registers ----
    float wr[HDIM], wz[HDIM], wn[HDIM];
    #pragma unroll
    for (int k = 0; k < HDIM; ++k) {
        wr[k] = eWhh[(j           ) * HDIM + k];
        wz[k] = eWhh[(j +   HDIM  ) * HDIM + k];
        wn[k] = eWhh[(j + 2*HDIM  ) * HDIM + k];
    }
    const float wir = eWih[j], wiz = eWih[j + HDIM], win = eWih[j + 2*HDIM];
    const float bir = ebih[j], biz = ebih[j + HDIM], bin_ = ebih[j + 2*HDIM];
    const float bhr = ebhh[j], bhz = ebhh[j + HDIM], bhn = ebhh[j + 2*HDIM];
    __syncthreads();   // xs ready (single wave; outside the hot loop)

    // ---- hidden state: hb[k] wave-uniform (SGPRs), hj = own component ----
    float hb[HDIM];
    #pragma unroll
    for (int k = 0; k < HDIM; ++k) hb[k] = 0.0f;
    float hj = 0.0f;

    // ================= encoder: 4096 sequential GRU steps =================
    for (int s = 0; s < SEQ_L; ++s) {
        const float xr = xs[s];
        float ar = bhr, az = bhz, an = bhn;
        #pragma unroll
        for (int k = 0; k < HDIM; ++k) {
            ar = fmaf(wr[k], hb[k], ar);
            az = fmaf(wz[k], hb[k], az);
            an = fmaf(wn[k], hb[k], an);
        }
        const float ir  = fmaf(xr, wir, bir);
        const float iz  = fmaf(xr, wiz, biz);
        const float inn = fmaf(xr, win, bin_);
        const float rg = fast_sig(ir + ar);
        const float zg = fast_sig(iz + az);
        const float ng = fast_tanh(fmaf(rg, an, inn));
        hj = (1.0f - zg) * ng + zg * hj;
        #pragma unroll
        for (int k = 0; k < HDIM; ++k) hb[k] = bcast_lane(hj, k);
    }
    // hb now holds h_enc, uniform across the wave.

    // ---- decoder weights ----
    float ur[HDIM], uz[HDIM], un[HDIM];   // dWih rows (r,z,n)
    float vr[HDIM], vz[HDIM], vn[HDIM];   // dWhh rows (r,z,n)
    #pragma unroll
    for (int k = 0; k < HDIM; ++k) {
        ur[k] = dWih[(j           ) * HDIM + k];
        uz[k] = dWih[(j +   HDIM  ) * HDIM + k];
        un[k] = dWih[(j + 2*HDIM  ) * HDIM + k];
        vr[k] = dWhh[(j           ) * HDIM + k];
        vz[k] = dWhh[(j +   HDIM  ) * HDIM + k];
        vn[k] = dWhh[(j + 2*HDIM  ) * HDIM + k];
    }
    const float bri = dbih[j], bzi = dbih[j + HDIM], bni = dbih[j + 2*HDIM];
    const float brh = dbhh[j], bzh = dbhh[j + HDIM], bnh = dbhh[j + 2*HDIM];
    const float lwj = linW[j];
    const float lb  = linb[0];

    // ---- decoder step 1: x = h_enc (in hb), h = ones ----
    float hd;
    {
        float ir = bri, iz = bzi, inn = bni;
        #pragma unroll
        for (int k = 0; k < HDIM; ++k) {
            ir  = fmaf(ur[k], hb[k], ir);
            iz  = fmaf(uz[k], hb[k], iz);
            inn = fmaf(un[k], hb[k], inn);
        }
        float hr = brh, hz = bzh, hn = bnh;
        #pragma unroll
        for (int k = 0; k < HDIM; ++k) { hr += vr[k]; hz += vz[k]; hn += vn[k]; }
        const float rg = fast_sig(ir + hr);
        const float zg = fast_sig(iz + hz);
        const float ng = fast_tanh(fmaf(rg, hn, inn));
        hd = (1.0f - zg) * ng + zg;        // h = 1
        float c = act ? lwj * hd : 0.0f;
        #pragma unroll
        for (int m = 32; m >= 1; m >>= 1) c += __shfl_xor(c, m, 64);
        if (t == 0) out[0] = c + lb;
        #pragma unroll
        for (int k = 0; k < HDIM; ++k) hb[k] = bcast_lane(hd, k);
    }

    // For steps >= 2, x == h, so r/z gates use combined weights (Wih+Whh);
    // n gate keeps i_n and h_n separate (n = tanh(i_n + r*h_n)).
    #pragma unroll
    for (int k = 0; k < HDIM; ++k) { vr[k] += ur[k]; vz[k] += uz[k]; }
    const float bcr = bri + brh, bcz = bzi + bzh;

    // ---- decoder steps 2..100 ----
    for (int s = 1; s < DEC_N; ++s) {
        float ar = bcr, az = bcz, i_n = bni, h_n = bnh;
        #pragma unroll
        for (int k = 0; k < HDIM; ++k) {
            ar  = fmaf(vr[k], hb[k], ar);
            az  = fmaf(vz[k], hb[k], az);
            i_n = fmaf(un[k], hb[k], i_n);
            h_n = fmaf(vn[k], hb[k], h_n);
        }
        const float rg = fast_sig(ar);
        const float zg = fast_sig(az);
        const float ng = fast_tanh(fmaf(rg, h_n, i_n));
        hd = (1.0f - zg) * ng + zg * hd;
        float c = act ? lwj * hd : 0.0f;
        #pragma unroll
        for (int m = 32; m >= 1; m >>= 1) c += __shfl_xor(c, m, 64);
        if (t == 0) out[s] = c + lb;
        #pragma unroll
        for (int k = 0; k < HDIM; ++k) hb[k] = bcast_lane(hd, k);
    }
}

extern "C" void kernel_launch(void* const* d_in, const int* in_sizes, int n_in,
                              void* d_out, int out_size, void* d_ws, size_t ws_size,
                              hipStream_t stream) {
    (void)in_sizes; (void)n_in; (void)d_ws; (void)ws_size; (void)out_size;
    seq2seq_gru_kernel<<<dim3(1), dim3(64), 0, stream>>>(
        (const float*)d_in[0],
        (const float*)d_in[1], (const float*)d_in[2],
        (const float*)d_in[3], (const float*)d_in[4],
        (const float*)d_in[5], (const float*)d_in[6],
        (const float*)d_in[7], (const float*)d_in[8],
        (const float*)d_in[9], (const float*)d_in[10],
        (float*)d_out);
}

// Round 4
// 853.876 us; speedup vs baseline: 2.1536x; 1.5606x over previous
//
#include <hip/hip_runtime.h>

#define SEQ_L 4096
#define HDIM  30
#define DEC_N 100

typedef float v2f __attribute__((ext_vector_type(2)));

#define NLc (-1.44269504088896340736f)   // -log2(e): sigmoid prescale
#define TLc ( 2.88539008177792681472f)   // 2*log2(e): tanh prescale

__device__ __forceinline__ float sig2(float sp) {   // sp = NLc * x  -> sigmoid(x)
    return __builtin_amdgcn_rcpf(1.0f + __builtin_amdgcn_exp2f(sp));
}
__device__ __forceinline__ float tanh2(float tp) {  // tp = TLc * x  -> tanh(x)
    return fmaf(-2.0f, __builtin_amdgcn_rcpf(1.0f + __builtin_amdgcn_exp2f(tp)), 1.0f);
}
__device__ __forceinline__ v2f mk2(float a, float b) { v2f r; r.x = a; r.y = b; return r; }

// One block, one wave. Unit j is computed by lanes j (k=0..15) and j+32
// (k=16..31, incl. pad slots 30=x, 31=1 carrying the x-term and biases).
// h is broadcast each step through a 32-float LDS buffer (ds_write_b32 +
// 8x ds_read_b64; single-wave LDS is in-order, no barrier needed).
__global__ __launch_bounds__(64, 1) void seq2seq_gru_kernel(
    const float* __restrict__ x,
    const float* __restrict__ eWih, const float* __restrict__ eWhh,
    const float* __restrict__ ebih, const float* __restrict__ ebhh,
    const float* __restrict__ dWih, const float* __restrict__ dWhh,
    const float* __restrict__ dbih, const float* __restrict__ dbhh,
    const float* __restrict__ linW, const float* __restrict__ linb,
    float* __restrict__ out)
{
    const int t    = threadIdx.x;
    const int l    = t & 31;
    const int half = t >> 5;
    const int j    = (l < HDIM) ? l : (HDIM - 1);
    const int rbase = half * 8;          // v2f index of this lane's k-range

    __shared__ __align__(16) float xs[SEQ_L + 4];
    __shared__ __align__(16) float hbuf[32];

    {   // stage x (vectorized); zero prefetch pad
        const float4* x4 = (const float4*)x;
        float4* s4 = (float4*)xs;
        #pragma unroll 4
        for (int i = t; i < SEQ_L / 4; i += 64) s4[i] = x4[i];
        if (t < 4) xs[SEQ_L + t] = 0.0f;
    }

    // ---- encoder weights: prescaled v2f pairs over this lane's k-range ----
    v2f wr[8], wz[8], wn[8];
    {
        const float* Rr = eWhh + (j         ) * HDIM;
        const float* Rz = eWhh + (j +  HDIM ) * HDIM;
        const float* Rn = eWhh + (j + 2*HDIM) * HDIM;
        #pragma unroll
        for (int m = 0; m < 8; ++m) {
            const int k = half * 16 + 2 * m;
            float r0=0.f,r1=0.f,z0=0.f,z1=0.f,n0=0.f,n1=0.f;
            if (k     < HDIM) { r0 = Rr[k];   z0 = Rz[k];   n0 = Rn[k];   }
            if (k + 1 < HDIM) { r1 = Rr[k+1]; z1 = Rz[k+1]; n1 = Rn[k+1]; }
            wr[m] = mk2(NLc * r0, NLc * r1);
            wz[m] = mk2(NLc * z0, NLc * z1);
            wn[m] = mk2(TLc * n0, TLc * n1);
        }
        if (half) {  // pad pair 7 multiplies (hbuf[30]=x, hbuf[31]=1)
            wr[7] = mk2(NLc * eWih[j],        NLc * (ebih[j] + ebhh[j]));
            wz[7] = mk2(NLc * eWih[j + HDIM], NLc * (ebih[j + HDIM] + ebhh[j + HDIM]));
            wn[7] = mk2(0.0f,                 TLc * ebhh[j + 2*HDIM]);
        }
    }
    const float win_ = TLc * eWih[j + 2*HDIM];
    const float bni  = TLc * ebih[j + 2*HDIM];

    __syncthreads();    // xs staged (one-time)
    if (t < 32) hbuf[t] = (t < HDIM) ? 0.0f : ((t == 30) ? xs[0] : 1.0f);

    const v2f* hb2 = (const v2f*)hbuf;
    float hj = 0.0f;
    float xr = xs[0];

    // ================= encoder: 4096 sequential GRU steps =================
    for (int s = 0; s < SEQ_L; ++s) {
        const float xnext = xs[s + 1];
        v2f g[8];
        #pragma unroll
        for (int m = 0; m < 8; ++m) g[m] = hb2[rbase + m];
        v2f a2 = g[0] * wr[0], b2 = g[0] * wz[0], c2 = g[0] * wn[0];
        #pragma unroll
        for (int m = 1; m < 8; ++m) {
            a2 += g[m] * wr[m];
            b2 += g[m] * wz[m];
            c2 += g[m] * wn[m];
        }
        float pr = a2.x + a2.y;    // NL*(Wr.h + Wir.x + br)  after combine
        float pz = b2.x + b2.y;
        float pn = c2.x + c2.y;    // TL*(Wn.h + bhn)         after combine
        pr += __shfl_xor(pr, 32);
        pz += __shfl_xor(pz, 32);
        pn += __shfl_xor(pn, 32);
        const float rg = sig2(pr);
        const float zg = sig2(pz);
        const float ng = tanh2(fmaf(rg, pn, fmaf(xr, win_, bni)));
        hj = fmaf(zg, hj - ng, ng);          // (1-z)*n + z*h
        hbuf[l] = (l < HDIM) ? hj : ((l == 30) ? xnext : 1.0f);
        xr = xnext;
    }
    // hbuf[0..29] = h_enc, hbuf[30] = xs[4096] = 0, hbuf[31] = 1

    // ---- decoder weights ----
    v2f ur[8], uz[8], un[8], vr[8], vz[8], vn[8];
    {
        const float* R0 = dWih + (j         ) * HDIM;
        const float* R1 = dWih + (j +  HDIM ) * HDIM;
        const float* R2 = dWih + (j + 2*HDIM) * HDIM;
        const float* R3 = dWhh + (j         ) * HDIM;
        const float* R4 = dWhh + (j +  HDIM ) * HDIM;
        const float* R5 = dWhh + (j + 2*HDIM) * HDIM;
        #pragma unroll
        for (int m = 0; m < 8; ++m) {
            const int k = half * 16 + 2 * m;
            float a0=0,a1=0,b0=0,b1=0,c0=0,c1=0,d0=0,d1=0,e0=0,e1=0,f0=0,f1=0;
            if (k     < HDIM) { a0=R0[k];   b0=R1[k];   c0=R2[k];   d0=R3[k];   e0=R4[k];   f0=R5[k];   }
            if (k + 1 < HDIM) { a1=R0[k+1]; b1=R1[k+1]; c1=R2[k+1]; d1=R3[k+1]; e1=R4[k+1]; f1=R5[k+1]; }
            ur[m] = mk2(NLc*a0, NLc*a1);  uz[m] = mk2(NLc*b0, NLc*b1);  un[m] = mk2(TLc*c0, TLc*c1);
            vr[m] = mk2(NLc*d0, NLc*d1);  vz[m] = mk2(NLc*e0, NLc*e1);  vn[m] = mk2(TLc*f0, TLc*f1);
        }
        if (half) {   // slot31 (==1) carries the biases; ur/uz pads stay 0
            un[7] = mk2(0.f, TLc * dbih[j + 2*HDIM]);
            vr[7] = mk2(0.f, NLc * (dbih[j] + dbhh[j]));
            vz[7] = mk2(0.f, NLc * (dbih[j + HDIM] + dbhh[j + HDIM]));
            vn[7] = mk2(0.f, TLc * dbhh[j + 2*HDIM]);
        }
    }
    // row sums over Whh (incl. bias pads) for decoder step 1 (h = ones)
    float vrs = 0.f, vzs = 0.f, vns = 0.f;
    #pragma unroll
    for (int m = 0; m < 8; ++m) {
        vrs += vr[m].x + vr[m].y;
        vzs += vz[m].x + vz[m].y;
        vns += vn[m].x + vn[m].y;
    }
    vrs += __shfl_xor(vrs, 32);
    vzs += __shfl_xor(vzs, 32);
    vns += __shfl_xor(vns, 32);
    const float lw = linW[j];
    const float lb = linb[0];
    const bool actA = (t < HDIM);

    float hd;
    // ---- decoder step 1: x = h_enc (from hbuf), h = ones ----
    {
        v2f g[8];
        #pragma unroll
        for (int m = 0; m < 8; ++m) g[m] = hb2[rbase + m];
        v2f a2 = g[0]*ur[0], b2 = g[0]*uz[0], c2 = g[0]*un[0];
        #pragma unroll
        for (int m = 1; m < 8; ++m) { a2 += g[m]*ur[m]; b2 += g[m]*uz[m]; c2 += g[m]*un[m]; }
        float pr = a2.x + a2.y, pz = b2.x + b2.y, pin = c2.x + c2.y;
        pr += __shfl_xor(pr, 32); pz += __shfl_xor(pz, 32); pin += __shfl_xor(pin, 32);
        pr += vrs; pz += vzs;
        const float rg = sig2(pr), zg = sig2(pz);
        const float ng = tanh2(fmaf(rg, vns, pin));
        hd = fmaf(zg, 1.0f - ng, ng);        // h = 1
        float c = actA ? lw * hd : 0.f;
        #pragma unroll
        for (int m = 16; m >= 1; m >>= 1) c += __shfl_xor(c, m);
        if (t == 0) out[0] = c + lb;
        hbuf[l] = (l < HDIM) ? hd : ((l == 30) ? 0.0f : 1.0f);
    }
    // steps >= 2: x == h -> fuse Wih+Whh for r,z (pads fuse to the bias pair)
    #pragma unroll
    for (int m = 0; m < 8; ++m) { ur[m] += vr[m]; uz[m] += vz[m]; }

    // ---- decoder steps 2..100 ----
    for (int s = 1; s < DEC_N; ++s) {
        v2f g[8];
        #pragma unroll
        for (int m = 0; m < 8; ++m) g[m] = hb2[rbase + m];
        v2f a2 = g[0]*ur[0], b2 = g[0]*uz[0], c2 = g[0]*un[0], d2 = g[0]*vn[0];
        #pragma unroll
        for (int m = 1; m < 8; ++m) {
            a2 += g[m]*ur[m]; b2 += g[m]*uz[m]; c2 += g[m]*un[m]; d2 += g[m]*vn[m];
        }
        float pr = a2.x + a2.y, pz = b2.x + b2.y, pin = c2.x + c2.y, phn = d2.x + d2.y;
        pr  += __shfl_xor(pr, 32);  pz  += __shfl_xor(pz, 32);
        pin += __shfl_xor(pin, 32); phn += __shfl_xor(phn, 32);
        const float rg = sig2(pr), zg = sig2(pz);
        const float ng = tanh2(fmaf(rg, phn, pin));
        hd = fmaf(zg, hd - ng, ng);
        float c = actA ? lw * hd : 0.f;
        #pragma unroll
        for (int m = 16; m >= 1; m >>= 1) c += __shfl_xor(c, m);
        if (t == 0) out[s] = c + lb;
        hbuf[l] = (l < HDIM) ? hd : ((l == 30) ? 0.0f : 1.0f);
    }
}

extern "C" void kernel_launch(void* const* d_in, const int* in_sizes, int n_in,
                              void* d_out, int out_size, void* d_ws, size_t ws_size,
                              hipStream_t stream) {
    (void)in_sizes; (void)n_in; (void)d_ws; (void)ws_size; (void)out_size;
    seq2seq_gru_kernel<<<dim3(1), dim3(64), 0, stream>>>(
        (const float*)d_in[0],
        (const float*)d_in[1], (const float*)d_in[2],
        (const float*)d_in[3], (const float*)d_in[4],
        (const float*)d_in[5], (const float*)d_in[6],
        (const float*)d_in[7], (const float*)d_in[8],
        (const float*)d_in[9], (const float*)d_in[10],
        (float*)d_out);
}

// Round 5
// 756.990 us; speedup vs baseline: 2.4292x; 1.1280x over previous
//
#include <hip/hip_runtime.h>

#define SEQ_L 4096
#define HDIM  30
#define DEC_N 100
#define HSTR  33   // padded history stride (bank-conflict-free final reads)

typedef float v2f __attribute__((ext_vector_type(2)));
typedef unsigned int v2u __attribute__((ext_vector_type(2)));

#define NLc (-1.44269504088896340736f)   // -log2(e): sigmoid prescale
#define TLc ( 2.88539008177792681472f)   // 2*log2(e): tanh prescale

__device__ __forceinline__ float sig2(float sp) {   // sp = NLc * x  -> sigmoid(x)
    return __builtin_amdgcn_rcpf(1.0f + __builtin_amdgcn_exp2f(sp));
}
__device__ __forceinline__ float tanh2(float tp) {  // tp = TLc * x  -> tanh(x)
    return fmaf(-2.0f, __builtin_amdgcn_rcpf(1.0f + __builtin_amdgcn_exp2f(tp)), 1.0f);
}
__device__ __forceinline__ v2f mk2(float a, float b) { v2f r; r.x = a; r.y = b; return r; }

// lane-l result = p[l] + p[l^32], via VALU permlane (no DS pipe, unlike shfl).
__device__ __forceinline__ float combine32(float p) {
    v2u r = __builtin_amdgcn_permlane32_swap(__float_as_uint(p), __float_as_uint(p),
                                             false, false);
    return __uint_as_float(r.x) + __uint_as_float(r.y);
}

// One block, one wave. Unit j handled by lanes j (k=0..15) and j+32 (k=16..31;
// pad slots 30=x, 31=1 carry x-terms and biases). h broadcast through a
// 32-float LDS buffer (single-wave DS is in-order -> no barrier); cross-half
// gate combine via v_permlane32_swap (VALU).
__global__ __launch_bounds__(64, 1) void seq2seq_gru_kernel(
    const float* __restrict__ x,
    const float* __restrict__ eWih, const float* __restrict__ eWhh,
    const float* __restrict__ ebih, const float* __restrict__ ebhh,
    const float* __restrict__ dWih, const float* __restrict__ dWhh,
    const float* __restrict__ dbih, const float* __restrict__ dbhh,
    const float* __restrict__ linW, const float* __restrict__ linb,
    float* __restrict__ out)
{
    const int t    = threadIdx.x;
    const int l    = t & 31;
    const int half = t >> 5;
    const int j    = (l < HDIM) ? l : (HDIM - 1);
    const int rb4  = half * 4;                    // float4 index of k-range
    const int wslot = (l < HDIM) ? l : (HDIM - 1);
    const bool isx  = (l == 30);

    __shared__ __align__(16) float xs[SEQ_L + 4];
    __shared__ __align__(16) float hbuf[32];
    __shared__ __align__(16) float hist[DEC_N * HSTR];
    __shared__ __align__(16) float lws[32];

    {   // stage x (vectorized); zero prefetch pad; stage linW
        const float4* x4 = (const float4*)x;
        float4* s4 = (float4*)xs;
        #pragma unroll 4
        for (int i = t; i < SEQ_L / 4; i += 64) s4[i] = x4[i];
        if (t < 4) xs[SEQ_L + t] = 0.0f;
        if (t < 32) lws[t] = (t < HDIM) ? linW[t] : 0.0f;
    }

    // ---- encoder weights: prescaled v2f pairs over this lane's k-range ----
    v2f wr[8], wz[8], wn[8];
    {
        const float* Rr = eWhh + (j         ) * HDIM;
        const float* Rz = eWhh + (j +  HDIM ) * HDIM;
        const float* Rn = eWhh + (j + 2*HDIM) * HDIM;
        #pragma unroll
        for (int m = 0; m < 8; ++m) {
            const int k = half * 16 + 2 * m;
            float r0=0.f,r1=0.f,z0=0.f,z1=0.f,n0=0.f,n1=0.f;
            if (k     < HDIM) { r0 = Rr[k];   z0 = Rz[k];   n0 = Rn[k];   }
            if (k + 1 < HDIM) { r1 = Rr[k+1]; z1 = Rz[k+1]; n1 = Rn[k+1]; }
            wr[m] = mk2(NLc * r0, NLc * r1);
            wz[m] = mk2(NLc * z0, NLc * z1);
            wn[m] = mk2(TLc * n0, TLc * n1);
        }
        if (half) {  // pad pair 7 multiplies (hbuf[30]=x, hbuf[31]=1)
            wr[7] = mk2(NLc * eWih[j],        NLc * (ebih[j] + ebhh[j]));
            wz[7] = mk2(NLc * eWih[j + HDIM], NLc * (ebih[j + HDIM] + ebhh[j + HDIM]));
            wn[7] = mk2(0.0f,                 TLc * ebhh[j + 2*HDIM]);
        }
    }
    const float win_ = TLc * eWih[j + 2*HDIM];
    const float bni  = TLc * ebih[j + 2*HDIM];

    __syncthreads();    // xs staged (one-time)
    if (t < 32) hbuf[t] = (t < HDIM) ? 0.0f : ((t == 30) ? xs[0] : 1.0f);

    const float4* hb4 = (const float4*)hbuf;
    float hj = 0.0f;
    float xr = xs[0];

    // ================= encoder: 4096 sequential GRU steps =================
    #pragma unroll 2
    for (int s = 0; s < SEQ_L; ++s) {
        const float xnext = xs[s + 1];
        float4 qa = hb4[rb4+0], qb = hb4[rb4+1], qc = hb4[rb4+2], qd = hb4[rb4+3];
        if (isx) hbuf[30] = xnext;   // DS-ordered after the reads; off value-chain
        v2f g[8] = { mk2(qa.x,qa.y), mk2(qa.z,qa.w), mk2(qb.x,qb.y), mk2(qb.z,qb.w),
                     mk2(qc.x,qc.y), mk2(qc.z,qc.w), mk2(qd.x,qd.y), mk2(qd.z,qd.w) };
        v2f a2 = g[0] * wr[0], b2 = g[0] * wz[0], c2 = g[0] * wn[0];
        #pragma unroll
        for (int m = 1; m < 8; ++m) {
            a2 += g[m] * wr[m];
            b2 += g[m] * wz[m];
            c2 += g[m] * wn[m];
        }
        const float pr = combine32(a2.x + a2.y);
        const float pz = combine32(b2.x + b2.y);
        const float pn = combine32(c2.x + c2.y);
        const float rg = sig2(pr);
        const float zg = sig2(pz);
        const float ng = tanh2(fmaf(rg, pn, fmaf(xr, win_, bni)));
        hj = fmaf(zg, hj - ng, ng);          // (1-z)*n + z*h
        hbuf[wslot] = hj;                    // lanes 30/31 dup-write slot 29
        xr = xnext;
    }
    // hbuf[0..29] = h_enc, hbuf[30] = xs[4096] = 0, hbuf[31] = 1

    // ---- decoder weights ----
    v2f ur[8], uz[8], un[8], vr[8], vz[8], vn[8];
    {
        const float* R0 = dWih + (j         ) * HDIM;
        const float* R1 = dWih + (j +  HDIM ) * HDIM;
        const float* R2 = dWih + (j + 2*HDIM) * HDIM;
        const float* R3 = dWhh + (j         ) * HDIM;
        const float* R4 = dWhh + (j +  HDIM ) * HDIM;
        const float* R5 = dWhh + (j + 2*HDIM) * HDIM;
        #pragma unroll
        for (int m = 0; m < 8; ++m) {
            const int k = half * 16 + 2 * m;
            float a0=0,a1=0,b0=0,b1=0,c0=0,c1=0,d0=0,d1=0,e0=0,e1=0,f0=0,f1=0;
            if (k     < HDIM) { a0=R0[k];   b0=R1[k];   c0=R2[k];   d0=R3[k];   e0=R4[k];   f0=R5[k];   }
            if (k + 1 < HDIM) { a1=R0[k+1]; b1=R1[k+1]; c1=R2[k+1]; d1=R3[k+1]; e1=R4[k+1]; f1=R5[k+1]; }
            ur[m] = mk2(NLc*a0, NLc*a1);  uz[m] = mk2(NLc*b0, NLc*b1);  un[m] = mk2(TLc*c0, TLc*c1);
            vr[m] = mk2(NLc*d0, NLc*d1);  vz[m] = mk2(NLc*e0, NLc*e1);  vn[m] = mk2(TLc*f0, TLc*f1);
        }
        if (half) {   // slot31 (==1) carries the biases; ur/uz pads stay 0
            un[7] = mk2(0.f, TLc * dbih[j + 2*HDIM]);
            vr[7] = mk2(0.f, NLc * (dbih[j] + dbhh[j]));
            vz[7] = mk2(0.f, NLc * (dbih[j + HDIM] + dbhh[j + HDIM]));
            vn[7] = mk2(0.f, TLc * dbhh[j + 2*HDIM]);
        }
    }
    // row sums over Whh (incl. bias pads) for decoder step 1 (h = ones)
    float vrs = 0.f, vzs = 0.f, vns = 0.f;
    #pragma unroll
    for (int m = 0; m < 8; ++m) {
        vrs += vr[m].x + vr[m].y;
        vzs += vz[m].x + vz[m].y;
        vns += vn[m].x + vn[m].y;
    }
    vrs = combine32(vrs);
    vzs = combine32(vzs);
    vns = combine32(vns);
    const float lb = linb[0];

    float hd;
    // ---- decoder step 1: x = h_enc (from hbuf), h = ones ----
    {
        float4 qa = hb4[rb4+0], qb = hb4[rb4+1], qc = hb4[rb4+2], qd = hb4[rb4+3];
        v2f g[8] = { mk2(qa.x,qa.y), mk2(qa.z,qa.w), mk2(qb.x,qb.y), mk2(qb.z,qb.w),
                     mk2(qc.x,qc.y), mk2(qc.z,qc.w), mk2(qd.x,qd.y), mk2(qd.z,qd.w) };
        v2f a2 = g[0]*ur[0], b2 = g[0]*uz[0], c2 = g[0]*un[0];
        #pragma unroll
        for (int m = 1; m < 8; ++m) { a2 += g[m]*ur[m]; b2 += g[m]*uz[m]; c2 += g[m]*un[m]; }
        const float pr  = combine32(a2.x + a2.y) + vrs;
        const float pz  = combine32(b2.x + b2.y) + vzs;
        const float pin = combine32(c2.x + c2.y);
        const float rg = sig2(pr), zg = sig2(pz);
        const float ng = tanh2(fmaf(rg, vns, pin));
        hd = fmaf(zg, 1.0f - ng, ng);        // h = 1
        hbuf[wslot] = hd;
        hist[0 * HSTR + wslot] = hd;
    }
    // steps >= 2: x == h -> fuse Wih+Whh for r,z (pads fuse to the bias pair)
    #pragma unroll
    for (int m = 0; m < 8; ++m) { ur[m] += vr[m]; uz[m] += vz[m]; }

    // ---- decoder steps 2..100 (outputs deferred to the end) ----
    for (int s = 1; s < DEC_N; ++s) {
        float4 qa = hb4[rb4+0], qb = hb4[rb4+1], qc = hb4[rb4+2], qd = hb4[rb4+3];
        v2f g[8] = { mk2(qa.x,qa.y), mk2(qa.z,qa.w), mk2(qb.x,qb.y), mk2(qb.z,qb.w),
                     mk2(qc.x,qc.y), mk2(qc.z,qc.w), mk2(qd.x,qd.y), mk2(qd.z,qd.w) };
        v2f a2 = g[0]*ur[0], b2 = g[0]*uz[0], c2 = g[0]*un[0], d2 = g[0]*vn[0];
        #pragma unroll
        for (int m = 1; m < 8; ++m) {
            a2 += g[m]*ur[m]; b2 += g[m]*uz[m]; c2 += g[m]*un[m]; d2 += g[m]*vn[m];
        }
        const float pr  = combine32(a2.x + a2.y);
        const float pz  = combine32(b2.x + b2.y);
        const float pin = combine32(c2.x + c2.y);
        const float phn = combine32(d2.x + d2.y);
        const float rg = sig2(pr), zg = sig2(pz);
        const float ng = tanh2(fmaf(rg, phn, pin));
        hd = fmaf(zg, hd - ng, ng);
        hbuf[wslot] = hd;
        hist[s * HSTR + wslot] = hd;
    }

    // ---- outputs: 100 parallel dot products from the LDS history ----
    #pragma unroll
    for (int b = 0; b < 2; ++b) {
        const int s = t + b * 64;
        if (s < DEC_N) {
            const float* hp = hist + s * HSTR;
            float acc = lb;
            #pragma unroll
            for (int k = 0; k < HDIM; ++k) acc = fmaf(lws[k], hp[k], acc);
            out[s] = acc;
        }
    }
}

extern "C" void kernel_launch(void* const* d_in, const int* in_sizes, int n_in,
                              void* d_out, int out_size, void* d_ws, size_t ws_size,
                              hipStream_t stream) {
    (void)in_sizes; (void)n_in; (void)d_ws; (void)ws_size; (void)out_size;
    seq2seq_gru_kernel<<<dim3(1), dim3(64), 0, stream>>>(
        (const float*)d_in[0],
        (const float*)d_in[1], (const float*)d_in[2],
        (const float*)d_in[3], (const float*)d_in[4],
        (const float*)d_in[5], (const float*)d_in[6],
        (const float*)d_in[7], (const float*)d_in[8],
        (const float*)d_in[9], (const float*)d_in[10],
        (float*)d_out);
}